// Round 1
// baseline (364.432 us; speedup 1.0000x reference)
//
#include <hip/hip_runtime.h>
#include <hip/hip_fp16.h>

#define N_NODES 100000
#define N_EDGES 3200000
#define N_PAD   100096
#define BNODES  128
#define NBUCK   ((N_NODES + BNODES - 1) / BNODES)       // 782
#define BCAP    4800                                    // mean 4096, sigma 64 (11 sigma)
#define EPB_BIN 8192                                    // edges per bin block (32/thread)
#define BIN_BLOCKS ((N_EDGES + EPB_BIN - 1) / EPB_BIN)  // 391
#define SPILL_MAX 65536
#define WQSCALE  32767.0f
#define NPX      (N_NODES / 8)                          // 12500 nodes per XCD slab
#define SCAN_CHUNK 2048
#define SCAN_BLOCKS ((N_NODES + SCAN_CHUNK - 1) / SCAN_CHUNK)

typedef unsigned int uint;
typedef unsigned short ushort;

__device__ __forceinline__ __half2 as_h2(uint u) { return *reinterpret_cast<__half2*>(&u); }
__device__ __forceinline__ uint as_u32(__half2 h) { return *reinterpret_cast<uint*>(&h); }

// ===================== fast path: bin -> sort -> nrm -> gather =====================

// prologue: x -> fp16, zero bucket_cnt/spill_cnt
__global__ __launch_bounds__(256) void k_pre(const float* __restrict__ x,
                                             __half* __restrict__ x16,
                                             int* __restrict__ bucket_cnt,
                                             int* __restrict__ spill_cnt) {
    int i = blockIdx.x * blockDim.x + threadIdx.x;
    if (i < N_NODES * 16) x16[i] = __float2half(x[i]);
    if (i < NBUCK) bucket_cnt[i] = 0;
    if (i == 0) *spill_cnt = 0;
}

// counting-sort edges into 782 dst-buckets; entry = { (dstl<<17)|src , w_bits }
__global__ __launch_bounds__(256) void k_bin(const int* __restrict__ src,
                                             const int* __restrict__ dst,
                                             const float* __restrict__ w,
                                             int* __restrict__ bucket_cnt,
                                             uint2* __restrict__ ebuf,
                                             int4* __restrict__ sp,
                                             int* __restrict__ spill_cnt) {
    __shared__ int hist[NBUCK];
    __shared__ int base[NBUCK];
    __shared__ int rank[NBUCK];
    int tid = threadIdx.x;
    for (int b = tid; b < NBUCK; b += 256) { hist[b] = 0; rank[b] = 0; }
    __syncthreads();
    int e0 = blockIdx.x * EPB_BIN;
#pragma unroll 4
    for (int k = 0; k < 32; k++) {
        int e = e0 + tid + k * 256;
        if (e < N_EDGES) atomicAdd(&hist[__builtin_nontemporal_load(dst + e) >> 7], 1);
    }
    __syncthreads();
    for (int b = tid; b < NBUCK; b += 256) {
        int c = hist[b];
        base[b] = c ? atomicAdd(&bucket_cnt[b], c) : 0;
    }
    __syncthreads();
#pragma unroll 4
    for (int k = 0; k < 32; k++) {
        int e = e0 + tid + k * 256;
        if (e < N_EDGES) {
            int s = __builtin_nontemporal_load(src + e);
            int d = __builtin_nontemporal_load(dst + e);
            float wv = __builtin_nontemporal_load(w + e);
            int b = d >> 7;
            int r = atomicAdd(&rank[b], 1);
            int pos = base[b] + r;
            if (pos < BCAP) {
                ebuf[(size_t)b * BCAP + pos] =
                    make_uint2(((uint)(d & 127) << 17) | (uint)s, __float_as_uint(wv));
            } else {
                int oi = atomicAdd(spill_cnt, 1);
                if (oi < SPILL_MAX) sp[oi] = make_int4(s, d, __float_as_int(wv), 0);
            }
        }
    }
}

// per-bucket: stage in LDS, node-histogram + weighted degree, prefix, scatter to
// node-major 4B entries (overlaying the bucket's own ebuf region); write dinv/meta.
__global__ __launch_bounds__(256) void k_sort(uint2* __restrict__ ebuf,
                                              const int* __restrict__ bucket_cnt,
                                              const int4* __restrict__ sp,
                                              const int* __restrict__ spill_cnt,
                                              float* __restrict__ dinv,
                                              int2* __restrict__ meta) {
    __shared__ uint2 ent[BCAP];          // 38.4 KB
    __shared__ float wacc[BNODES];
    __shared__ int   hist[BNODES];
    __shared__ int   pref[BNODES];
    __shared__ int   curs[BNODES];
    int b = blockIdx.x, tid = threadIdx.x;
    int lo = b * BNODES;
    int n = N_NODES - lo; if (n > BNODES) n = BNODES;
    if (tid < BNODES) { wacc[tid] = 0.0f; hist[tid] = 0; }
    __syncthreads();
    int cnt = bucket_cnt[b]; if (cnt > BCAP) cnt = BCAP;
    const uint2* srcrow = ebuf + (size_t)b * BCAP;
    for (int j = tid; j < cnt; j += 256) {
        uint2 e = srcrow[j];
        ent[j] = e;
        int nl = e.x >> 17;
        atomicAdd(&hist[nl], 1);
        atomicAdd(&wacc[nl], __uint_as_float(e.y));
    }
    int ns = *spill_cnt; if (ns > SPILL_MAX) ns = SPILL_MAX;
    for (int i = tid; i < ns; i += 256) {
        int4 q = sp[i];
        if ((q.y >> 7) == b) atomicAdd(&wacc[q.y & 127], __int_as_float(q.z));
    }
    __syncthreads();
    // inclusive prefix over hist -> pref
    if (tid < BNODES) pref[tid] = hist[tid];
    __syncthreads();
    for (int off = 1; off < BNODES; off <<= 1) {
        int v = 0;
        if (tid < BNODES && tid >= off) v = pref[tid - off];
        __syncthreads();
        if (tid < BNODES) pref[tid] += v;
        __syncthreads();
    }
    if (tid < BNODES) curs[tid] = pref[tid] - hist[tid];   // exclusive start
    if (tid < n) {
        meta[lo + tid] = make_int2(b * (BCAP * 2) + (pref[tid] - hist[tid]), hist[tid]);
        dinv[lo + tid] = rsqrtf(1.0f + wacc[tid]);
    }
    __syncthreads();
    // scatter node-sorted 4B entries over the bucket's own region (source is in LDS)
    uint* outb = (uint*)ebuf + (size_t)b * (BCAP * 2);
    for (int j = tid; j < cnt; j += 256) {
        uint2 e = ent[j];
        int nl = e.x >> 17;
        int pos = atomicAdd(&curs[nl], 1);
        uint wq = __float2uint_rn(__uint_as_float(e.y) * WQSCALE);
        outb[pos] = (wq << 17) | (e.x & 0x1FFFF);
    }
}

// fold dinv[src] into each sorted entry: q15(w) -> fp16-bits(dinv[s]*w)
// (positive fp16 < 1 has sign=0 -> the 16-bit pattern fits in 15 bits)
__global__ __launch_bounds__(256) void k_nrm(uint* __restrict__ sbuf,
                                             const int* __restrict__ bucket_cnt,
                                             const float* __restrict__ dinv) {
    int b = blockIdx.x, tid = threadIdx.x;
    int cnt = bucket_cnt[b]; if (cnt > BCAP) cnt = BCAP;
    uint* outb = sbuf + (size_t)b * (BCAP * 2);
    for (int j = tid; j < cnt; j += 256) {
        uint e = outb[j];
        int s = e & 0x1FFFF;
        float wv = (float)(e >> 17) * (1.0f / WQSCALE);
        __half h = __float2half(dinv[s] * wv);
        uint q = (uint)__half_as_ushort(h);           // <= 0x3C00, fits 15 bits
        outb[j] = (q << 17) | (uint)s;
    }
}

// fused: layer-1 gather (packed fp16 math, single-shot 2 edges/lane) + self + MLP.
__global__ __launch_bounds__(256) void k_gather_mlp(const uint* __restrict__ sbuf,
                                                    const int2* __restrict__ meta,
                                                    const int4* __restrict__ sp,
                                                    const int* __restrict__ spill_cnt,
                                                    const float* __restrict__ dinv,
                                                    const __half* __restrict__ x16,
                                                    const float* __restrict__ W1,
                                                    const float* __restrict__ b1,
                                                    const float* __restrict__ W2,
                                                    const float* __restrict__ b2,
                                                    __half* __restrict__ h2,
                                                    float* __restrict__ out) {
    __shared__ float fvs[4][16];
    __shared__ float o1s[4][128];
    int wave = threadIdx.x >> 6, lane = threadIdx.x & 63;
    int node = (blockIdx.x & 7) * NPX + (blockIdx.x >> 3) * 4 + wave;   // XCD slab
    int c2 = lane & 1, eo = lane >> 1;
    int2 mm = meta[node];
    int beg = mm.x, cnt = mm.y;
    float di = dinv[node];
    const uint* row = sbuf + beg;
    int j0 = 2 * eo, j1 = 2 * eo + 1;
    uint e0 = row[(j0 < cnt) ? j0 : 0];
    uint e1 = row[(j1 < cnt) ? j1 : 0];
    ushort qb0 = (j0 < cnt) ? (ushort)(e0 >> 17) : (ushort)0;
    ushort qb1 = (j1 < cnt) ? (ushort)(e1 >> 17) : (ushort)0;
    __half2 nq0 = __half2half2(__ushort_as_half(qb0));
    __half2 nq1 = __half2half2(__ushort_as_half(qb1));
    int s0 = e0 & 0x1FFFF, s1 = e1 & 0x1FFFF;
    uint4 hv0 = *(const uint4*)(x16 + (size_t)s0 * 16 + c2 * 8);
    uint4 hv1 = *(const uint4*)(x16 + (size_t)s1 * 16 + c2 * 8);
    __half2 acc[4];
    acc[0] = __hfma2(nq1, as_h2(hv1.x), __hmul2(nq0, as_h2(hv0.x)));
    acc[1] = __hfma2(nq1, as_h2(hv1.y), __hmul2(nq0, as_h2(hv0.y)));
    acc[2] = __hfma2(nq1, as_h2(hv1.z), __hmul2(nq0, as_h2(hv0.z)));
    acc[3] = __hfma2(nq1, as_h2(hv1.w), __hmul2(nq0, as_h2(hv0.w)));
    // rare tail: cnt > 64
    for (int j = 64 + 2 * eo; j < cnt; j += 64) {
        uint ea = row[j];
        uint eb = row[((j + 1) < cnt) ? (j + 1) : 0];
        ushort qa = (ushort)(ea >> 17);
        ushort qb = ((j + 1) < cnt) ? (ushort)(eb >> 17) : (ushort)0;
        __half2 na = __half2half2(__ushort_as_half(qa));
        __half2 nb = __half2half2(__ushort_as_half(qb));
        int sa = ea & 0x1FFFF, sb = eb & 0x1FFFF;
        uint4 ha = *(const uint4*)(x16 + (size_t)sa * 16 + c2 * 8);
        uint4 hb = *(const uint4*)(x16 + (size_t)sb * 16 + c2 * 8);
        acc[0] = __hfma2(nb, as_h2(hb.x), __hfma2(na, as_h2(ha.x), acc[0]));
        acc[1] = __hfma2(nb, as_h2(hb.y), __hfma2(na, as_h2(ha.y), acc[1]));
        acc[2] = __hfma2(nb, as_h2(hb.z), __hfma2(na, as_h2(ha.z), acc[2]));
        acc[3] = __hfma2(nb, as_h2(hb.w), __hfma2(na, as_h2(ha.w), acc[3]));
    }
#pragma unroll
    for (int m = 2; m < 64; m <<= 1) {
#pragma unroll
        for (int k = 0; k < 4; k++)
            acc[k] = __hadd2(acc[k], as_h2(__shfl_xor(as_u32(acc[k]), m, 64)));
    }
    if (lane < 2) {
        float accf[8];
#pragma unroll
        for (int k = 0; k < 4; k++) {
            float2 f = __half22float2(acc[k]);
            accf[2 * k + 0] = f.x;
            accf[2 * k + 1] = f.y;
        }
        uint4 hv = *(const uint4*)(x16 + (size_t)node * 16 + c2 * 8);
        float2 s0f = __half22float2(as_h2(hv.x));
        float2 s1f = __half22float2(as_h2(hv.y));
        float2 s2f = __half22float2(as_h2(hv.z));
        float2 s3f = __half22float2(as_h2(hv.w));
        float slf[8] = {s0f.x, s0f.y, s1f.x, s1f.y, s2f.x, s2f.y, s3f.x, s3f.y};
        float r[8];
#pragma unroll
        for (int k = 0; k < 8; k++) r[k] = accf[k] + di * slf[k];
        int ns = *spill_cnt;                       // 0 in practice
        if (ns > 0) {
            if (ns > SPILL_MAX) ns = SPILL_MAX;
            for (int i = 0; i < ns; i++) {
                int4 q = sp[i];
                if (q.y == node) {
                    float f = dinv[q.x] * __int_as_float(q.z);
                    uint4 qv = *(const uint4*)(x16 + (size_t)q.x * 16 + c2 * 8);
                    float2 u0 = __half22float2(as_h2(qv.x));
                    float2 u1 = __half22float2(as_h2(qv.y));
                    float2 u2 = __half22float2(as_h2(qv.z));
                    float2 u3 = __half22float2(as_h2(qv.w));
                    float uv[8] = {u0.x, u0.y, u1.x, u1.y, u2.x, u2.y, u3.x, u3.y};
                    for (int k = 0; k < 8; k++) r[k] += f * uv[k];
                }
            }
        }
#pragma unroll
        for (int k = 0; k < 8; k++) fvs[wave][c2 * 8 + k] = r[k] * di;
    }
    __syncthreads();
    float fv[16];
#pragma unroll
    for (int k = 0; k < 16; k++) fv[k] = fvs[wave][k];
    float a = b1[2 * lane], bb = b1[2 * lane + 1];
#pragma unroll
    for (int k = 0; k < 16; k++) {
        float2 wv = *(const float2*)(W1 + k * 128 + 2 * lane);
        a = fmaf(fv[k], wv.x, a);
        bb = fmaf(fv[k], wv.y, bb);
    }
    o1s[wave][2 * lane + 0] = fmaxf(a, 0.0f);
    o1s[wave][2 * lane + 1] = fmaxf(bb, 0.0f);
    __syncthreads();
    int c = lane & 15, g = lane >> 4;
    float p = 0.0f;
#pragma unroll
    for (int k = 0; k < 32; k++) {
        int kk = g * 32 + k;
        p = fmaf(o1s[wave][kk], W2[kk * 16 + c], p);
    }
    p += __shfl_down(p, 16, 64);
    p += __shfl_down(p, 32, 64);
    if (lane < 16) {
        h2[(size_t)node * 16 + c] = __float2half(p);
        out[(size_t)node * 16 + c] = di * di * p + b2[c];
    }
}

// layer-2 gather: out[node] += di * (sum q*h2[s] + spill); packed fp16 math.
__global__ __launch_bounds__(256) void k_gather2(const uint* __restrict__ sbuf,
                                                 const int2* __restrict__ meta,
                                                 const int4* __restrict__ sp,
                                                 const int* __restrict__ spill_cnt,
                                                 const float* __restrict__ dinv,
                                                 const __half* __restrict__ h2,
                                                 float* __restrict__ out) {
    int wave = threadIdx.x >> 6, lane = threadIdx.x & 63;
    int node = (blockIdx.x & 7) * NPX + (blockIdx.x >> 3) * 4 + wave;
    int c2 = lane & 1, eo = lane >> 1;
    int2 mm = meta[node];
    int beg = mm.x, cnt = mm.y;
    float di = dinv[node];
    const uint* row = sbuf + beg;
    int j0 = 2 * eo, j1 = 2 * eo + 1;
    uint e0 = row[(j0 < cnt) ? j0 : 0];
    uint e1 = row[(j1 < cnt) ? j1 : 0];
    ushort qb0 = (j0 < cnt) ? (ushort)(e0 >> 17) : (ushort)0;
    ushort qb1 = (j1 < cnt) ? (ushort)(e1 >> 17) : (ushort)0;
    __half2 nq0 = __half2half2(__ushort_as_half(qb0));
    __half2 nq1 = __half2half2(__ushort_as_half(qb1));
    int s0 = e0 & 0x1FFFF, s1 = e1 & 0x1FFFF;
    uint4 hv0 = *(const uint4*)(h2 + (size_t)s0 * 16 + c2 * 8);
    uint4 hv1 = *(const uint4*)(h2 + (size_t)s1 * 16 + c2 * 8);
    __half2 acc[4];
    acc[0] = __hfma2(nq1, as_h2(hv1.x), __hmul2(nq0, as_h2(hv0.x)));
    acc[1] = __hfma2(nq1, as_h2(hv1.y), __hmul2(nq0, as_h2(hv0.y)));
    acc[2] = __hfma2(nq1, as_h2(hv1.z), __hmul2(nq0, as_h2(hv0.z)));
    acc[3] = __hfma2(nq1, as_h2(hv1.w), __hmul2(nq0, as_h2(hv0.w)));
    for (int j = 64 + 2 * eo; j < cnt; j += 64) {
        uint ea = row[j];
        uint eb = row[((j + 1) < cnt) ? (j + 1) : 0];
        ushort qa = (ushort)(ea >> 17);
        ushort qb = ((j + 1) < cnt) ? (ushort)(eb >> 17) : (ushort)0;
        __half2 na = __half2half2(__ushort_as_half(qa));
        __half2 nb = __half2half2(__ushort_as_half(qb));
        int sa = ea & 0x1FFFF, sb = eb & 0x1FFFF;
        uint4 ha = *(const uint4*)(h2 + (size_t)sa * 16 + c2 * 8);
        uint4 hb = *(const uint4*)(h2 + (size_t)sb * 16 + c2 * 8);
        acc[0] = __hfma2(nb, as_h2(hb.x), __hfma2(na, as_h2(ha.x), acc[0]));
        acc[1] = __hfma2(nb, as_h2(hb.y), __hfma2(na, as_h2(ha.y), acc[1]));
        acc[2] = __hfma2(nb, as_h2(hb.z), __hfma2(na, as_h2(ha.z), acc[2]));
        acc[3] = __hfma2(nb, as_h2(hb.w), __hfma2(na, as_h2(ha.w), acc[3]));
    }
#pragma unroll
    for (int m = 2; m < 64; m <<= 1) {
#pragma unroll
        for (int k = 0; k < 4; k++)
            acc[k] = __hadd2(acc[k], as_h2(__shfl_xor(as_u32(acc[k]), m, 64)));
    }
    if (lane < 2) {
        float accf[8];
#pragma unroll
        for (int k = 0; k < 4; k++) {
            float2 f = __half22float2(acc[k]);
            accf[2 * k + 0] = f.x;
            accf[2 * k + 1] = f.y;
        }
        int ns = *spill_cnt;
        if (ns > 0) {
            if (ns > SPILL_MAX) ns = SPILL_MAX;
            for (int i = 0; i < ns; i++) {
                int4 q = sp[i];
                if (q.y == node) {
                    float f = dinv[q.x] * __int_as_float(q.z);
                    uint4 qv = *(const uint4*)(h2 + (size_t)q.x * 16 + c2 * 8);
                    float2 u0 = __half22float2(as_h2(qv.x));
                    float2 u1 = __half22float2(as_h2(qv.y));
                    float2 u2 = __half22float2(as_h2(qv.z));
                    float2 u3 = __half22float2(as_h2(qv.w));
                    float uv[8] = {u0.x, u0.y, u1.x, u1.y, u2.x, u2.y, u3.x, u3.y};
                    for (int k = 0; k < 8; k++) accf[k] += f * uv[k];
                }
            }
        }
        float4* op = (float4*)(out + (size_t)node * 16 + c2 * 8);
        float4 o0 = op[0], o1 = op[1];
        o0.x += di * accf[0]; o0.y += di * accf[1];
        o0.z += di * accf[2]; o0.w += di * accf[3];
        o1.x += di * accf[4]; o1.y += di * accf[5];
        o1.z += di * accf[6]; o1.w += di * accf[7];
        op[0] = o0; op[1] = o1;
    }
}

// ===================== CSR fallback (round-2) =====================

__global__ void k_init(float* __restrict__ deg, int* __restrict__ cnt) {
    int i = blockIdx.x * blockDim.x + threadIdx.x;
    if (i < N_NODES) { deg[i] = 1.0f; if (cnt) cnt[i] = 0; }
}

__global__ void k_degcnt(const int* __restrict__ dst, const float* __restrict__ w,
                         float* __restrict__ deg, int* __restrict__ cnt) {
    int e = blockIdx.x * blockDim.x + threadIdx.x;
    if (e < N_EDGES) {
        int d = dst[e];
        atomicAdd(&deg[d], w[e]);
        if (cnt) atomicAdd(&cnt[d], 1);
    }
}

__global__ void k_dinv_agg(const float* __restrict__ x, float* __restrict__ deg_dinv,
                           float* __restrict__ agg) {
    int i = blockIdx.x * blockDim.x + threadIdx.x;
    if (i >= N_NODES) return;
    float di = rsqrtf(deg_dinv[i]);
    deg_dinv[i] = di;
    float s = di * di;
    const float4* xr = (const float4*)(x + (size_t)i * 16);
    float4* ar = (float4*)(agg + (size_t)i * 16);
#pragma unroll
    for (int k = 0; k < 4; k++) {
        float4 v = xr[k];
        v.x *= s; v.y *= s; v.z *= s; v.w *= s;
        ar[k] = v;
    }
}

__global__ __launch_bounds__(256) void k_scan1(const int* __restrict__ cnt,
                                               int* __restrict__ rowptr,
                                               int* __restrict__ bsum) {
    __shared__ int ts[256];
    int tid = threadIdx.x;
    int base = blockIdx.x * SCAN_CHUNK + tid * 8;
    int v[8]; int s = 0;
#pragma unroll
    for (int k = 0; k < 8; k++) {
        int idx = base + k;
        v[k] = (idx < N_NODES) ? cnt[idx] : 0;
        s += v[k];
    }
    ts[tid] = s;
    __syncthreads();
    for (int off = 1; off < 256; off <<= 1) {
        int t = (tid >= off) ? ts[tid - off] : 0;
        __syncthreads();
        ts[tid] += t;
        __syncthreads();
    }
    int run = ts[tid] - s;
#pragma unroll
    for (int k = 0; k < 8; k++) {
        int idx = base + k;
        if (idx < N_NODES) rowptr[idx] = run;
        run += v[k];
    }
    if (tid == 255) bsum[blockIdx.x] = ts[255];
}

__global__ void k_scan2(int* __restrict__ bsum) {
    if (threadIdx.x == 0 && blockIdx.x == 0) {
        int run = 0;
        for (int g = 0; g < SCAN_BLOCKS; g++) { int t = bsum[g]; bsum[g] = run; run += t; }
    }
}

__global__ __launch_bounds__(256) void k_scan3(int* __restrict__ rowptr,
                                               const int* __restrict__ bsum) {
    int tid = threadIdx.x;
    int base = blockIdx.x * SCAN_CHUNK + tid * 8;
    int off = bsum[blockIdx.x];
#pragma unroll
    for (int k = 0; k < 8; k++) {
        int idx = base + k;
        if (idx < N_NODES) rowptr[idx] += off;
    }
    if (blockIdx.x == 0 && tid == 0) rowptr[N_NODES] = N_EDGES;
}

__global__ void k_fill(const int* __restrict__ src, const int* __restrict__ dst,
                       const float* __restrict__ w, const float* __restrict__ dinv,
                       const int* __restrict__ rowptr, int* __restrict__ cnt,
                       int2* __restrict__ perm) {
    int e = blockIdx.x * blockDim.x + threadIdx.x;
    if (e >= N_EDGES) return;
    int s = src[e], d = dst[e];
    float nrm = dinv[s] * w[e] * dinv[d];
    int r = atomicSub(&cnt[d], 1) - 1;
    int pos = rowptr[d] + r;
    perm[pos] = make_int2(s, __float_as_int(nrm));
}

__global__ __launch_bounds__(256) void k_gather(const int2* __restrict__ perm,
                                                const int* __restrict__ rowptr,
                                                const float* __restrict__ feat,
                                                float* __restrict__ out) {
    int wave = threadIdx.x >> 6, lane = threadIdx.x & 63;
    int node = blockIdx.x * 4 + wave;
    int c = lane & 15, eo = lane >> 4;
    int beg = rowptr[node], end = rowptr[node + 1];
    float acc = 0.0f;
    for (int j = beg + eo; j < end; j += 4) {
        int2 ed = perm[j];
        acc = fmaf(__int_as_float(ed.y), feat[(size_t)ed.x * 16 + c], acc);
    }
    acc += __shfl_xor(acc, 16, 64);
    acc += __shfl_xor(acc, 32, 64);
    if (lane < 16) out[(size_t)node * 16 + c] += acc;
}

__global__ __launch_bounds__(256) void k_mlp(float* __restrict__ agg,
                                             const float* __restrict__ W1,
                                             const float* __restrict__ b1,
                                             const float* __restrict__ W2,
                                             const float* __restrict__ b2,
                                             const float* __restrict__ dinv,
                                             float* __restrict__ out) {
    __shared__ float o1s[4][128];
    int wave = threadIdx.x >> 6;
    int lane = threadIdx.x & 63;
    int node = blockIdx.x * 4 + wave;
    const float* f = agg + (size_t)node * 16;
    float fv[16];
#pragma unroll
    for (int k = 0; k < 4; k++) {
        float4 v = ((const float4*)f)[k];
        fv[4 * k + 0] = v.x; fv[4 * k + 1] = v.y; fv[4 * k + 2] = v.z; fv[4 * k + 3] = v.w;
    }
    float a = b1[2 * lane], b = b1[2 * lane + 1];
#pragma unroll
    for (int k = 0; k < 16; k++) {
        float2 wv = *(const float2*)(W1 + k * 128 + 2 * lane);
        a = fmaf(fv[k], wv.x, a);
        b = fmaf(fv[k], wv.y, b);
    }
    o1s[wave][2 * lane + 0] = fmaxf(a, 0.0f);
    o1s[wave][2 * lane + 1] = fmaxf(b, 0.0f);
    __syncthreads();
    int c = lane & 15, g = lane >> 4;
    float p = 0.0f;
#pragma unroll
    for (int k = 0; k < 32; k++) {
        int kk = g * 32 + k;
        p = fmaf(o1s[wave][kk], W2[kk * 16 + c], p);
    }
    p += __shfl_down(p, 16, 64);
    p += __shfl_down(p, 32, 64);
    __syncthreads();
    if (lane < 16) {
        float h2v = p;
        agg[(size_t)node * 16 + c] = h2v;
        float di = dinv[node];
        out[(size_t)node * 16 + c] = di * di * h2v + b2[c];
    }
}

__global__ void k_scatter(const int* __restrict__ src, const int* __restrict__ dst,
                          const float* __restrict__ w, const float* __restrict__ dinv,
                          const float* __restrict__ feat, float* __restrict__ out) {
    int t = blockIdx.x * blockDim.x + threadIdx.x;
    int e = t >> 2;
    int c4 = (t & 3) * 4;
    if (e >= N_EDGES) return;
    int s = src[e], d = dst[e];
    float nrm = dinv[s] * w[e] * dinv[d];
    float4 v = *(const float4*)(feat + (size_t)s * 16 + c4);
    float* o = out + (size_t)d * 16 + c4;
    atomicAdd(o + 0, nrm * v.x);
    atomicAdd(o + 1, nrm * v.y);
    atomicAdd(o + 2, nrm * v.z);
    atomicAdd(o + 3, nrm * v.w);
}

// ===================== launch =====================

extern "C" void kernel_launch(void* const* d_in, const int* in_sizes, int n_in,
                              void* d_out, int out_size, void* d_ws, size_t ws_size,
                              hipStream_t stream) {
    const float* x  = (const float*)d_in[0];
    const int*   ei = (const int*)d_in[1];
    const float* w  = (const float*)d_in[2];
    const float* W1 = (const float*)d_in[3];
    const float* b1 = (const float*)d_in[4];
    const float* W2 = (const float*)d_in[5];
    const float* b2 = (const float*)d_in[6];
    float* out = (float*)d_out;

    const int* src = ei;
    const int* dst = ei + N_EDGES;
    const int B = 256;

    // ---- fast-path workspace layout (16B-aligned blocks) ----
    char* p = (char*)d_ws;
    int*    bucket_cnt = (int*)p;        p += (size_t)((NBUCK + 3) & ~3) * 4;
    int*    spill_cnt  = (int*)p;        p += 16;
    float*  dinv       = (float*)p;      p += (size_t)N_PAD * 4;
    int2*   meta       = (int2*)p;       p += (size_t)N_PAD * 8;
    __half* x16        = (__half*)p;     p += (size_t)N_NODES * 16 * 2;
    __half* h2         = (__half*)p;     p += (size_t)N_NODES * 16 * 2;
    int4*   sp         = (int4*)p;       p += (size_t)SPILL_MAX * 16;
    uint2*  ebuf       = (uint2*)p;      p += (size_t)NBUCK * BCAP * 8;
    const size_t WS_FAST = (size_t)(p - (char*)d_ws);

    if (ws_size >= WS_FAST) {
        k_pre<<<(N_NODES * 16 + B - 1) / B, B, 0, stream>>>(x, x16, bucket_cnt, spill_cnt);
        k_bin<<<BIN_BLOCKS, B, 0, stream>>>(src, dst, w, bucket_cnt, ebuf, sp, spill_cnt);
        k_sort<<<NBUCK, B, 0, stream>>>(ebuf, bucket_cnt, sp, spill_cnt, dinv, meta);
        k_nrm<<<NBUCK, B, 0, stream>>>((uint*)ebuf, bucket_cnt, dinv);
        k_gather_mlp<<<N_NODES / 4, B, 0, stream>>>((const uint*)ebuf, meta,
                                                    sp, spill_cnt, dinv, x16,
                                                    W1, b1, W2, b2, h2, out);
        k_gather2<<<N_NODES / 4, B, 0, stream>>>((const uint*)ebuf, meta,
                                                 sp, spill_cnt, dinv, h2, out);
        return;
    }

    // ---- CSR fallback (round-2 path) ----
    float* deg_dinv = (float*)d_ws;
    int*   cntb     = (int*)(deg_dinv + N_PAD);
    int*   rowptr   = cntb + N_PAD;
    int*   bsum     = rowptr + N_PAD;
    float* agg      = (float*)(bsum + 64);
    int2*  perm     = (int2*)(agg + (size_t)N_NODES * 16);
    const size_t WS_CSR = ((size_t)N_PAD * 3 + 64 + (size_t)N_NODES * 16) * 4
                          + (size_t)N_EDGES * 8;

    if (ws_size >= WS_CSR) {
        k_init<<<(N_NODES + B - 1) / B, B, 0, stream>>>(deg_dinv, cntb);
        k_degcnt<<<(N_EDGES + B - 1) / B, B, 0, stream>>>(dst, w, deg_dinv, cntb);
        k_dinv_agg<<<(N_NODES + B - 1) / B, B, 0, stream>>>(x, deg_dinv, agg);
        k_scan1<<<SCAN_BLOCKS, 256, 0, stream>>>(cntb, rowptr, bsum);
        k_scan2<<<1, 64, 0, stream>>>(bsum);
        k_scan3<<<SCAN_BLOCKS, 256, 0, stream>>>(rowptr, bsum);
        k_fill<<<(N_EDGES + B - 1) / B, B, 0, stream>>>(src, dst, w, deg_dinv,
                                                        rowptr, cntb, perm);
        k_gather<<<N_NODES / 4, B, 0, stream>>>(perm, rowptr, x, agg);
        k_mlp<<<N_NODES / 4, B, 0, stream>>>(agg, W1, b1, W2, b2, deg_dinv, out);
        k_gather<<<N_NODES / 4, B, 0, stream>>>(perm, rowptr, agg, out);
    } else {
        float* deg = (float*)d_ws;
        float* ag  = (float*)d_ws + N_NODES;
        k_init<<<(N_NODES + B - 1) / B, B, 0, stream>>>(deg, (int*)nullptr);
        k_degcnt<<<(N_EDGES + B - 1) / B, B, 0, stream>>>(dst, w, deg, (int*)nullptr);
        k_dinv_agg<<<(N_NODES + B - 1) / B, B, 0, stream>>>(x, deg, ag);
        k_scatter<<<((size_t)N_EDGES * 4 + B - 1) / B, B, 0, stream>>>(src, dst, w, deg, x, ag);
        k_mlp<<<N_NODES / 4, B, 0, stream>>>(ag, W1, b1, W2, b2, deg, out);
        k_scatter<<<((size_t)N_EDGES * 4 + B - 1) / B, B, 0, stream>>>(src, dst, w, deg, ag, out);
    }
}

// Round 2
// 357.435 us; speedup vs baseline: 1.0196x; 1.0196x over previous
//
#include <hip/hip_runtime.h>
#include <hip/hip_fp16.h>

#define N_NODES 100000
#define N_EDGES 3200000
#define N_PAD   100096
#define BNODES  128
#define NBUCK   ((N_NODES + BNODES - 1) / BNODES)       // 782
#define BCAP    4800                                    // mean 4096, sigma 64 (11 sigma)
#define EPB_BIN 8192                                    // edges per bin block (32/thread)
#define BIN_BLOCKS ((N_EDGES + EPB_BIN - 1) / EPB_BIN)  // 391
#define SPILL_MAX 65536
#define WQSCALE  32767.0f
#define NPX      (N_NODES / 8)                          // 12500 nodes per XCD slab
#define GBLK     (8 * ((NPX + 7) / 8))                  // 12504 gather blocks (8 nodes each)
#define SCAN_CHUNK 2048
#define SCAN_BLOCKS ((N_NODES + SCAN_CHUNK - 1) / SCAN_CHUNK)

typedef unsigned int uint;
typedef unsigned short ushort;

__device__ __forceinline__ __half2 as_h2(uint u) { return *reinterpret_cast<__half2*>(&u); }
__device__ __forceinline__ uint as_u32(__half2 h) { return *reinterpret_cast<uint*>(&h); }

// fixed-stride row address: node n's 64 slots live inside its bucket's region
// (bucket stride stays BCAP*2 uints so k_sort's in-place overlay never crosses buckets)
__device__ __forceinline__ size_t srow(int n) {
    return (size_t)(n >> 7) * (BCAP * 2) + (size_t)(n & 127) * 64;
}

// ===================== fast path: bin -> sort -> nrm -> gather =====================

// prologue: x -> fp16, zero bucket_cnt/spill_cnt
__global__ __launch_bounds__(256) void k_pre(const float* __restrict__ x,
                                             __half* __restrict__ x16,
                                             int* __restrict__ bucket_cnt,
                                             int* __restrict__ spill_cnt) {
    int i = blockIdx.x * blockDim.x + threadIdx.x;
    if (i < N_NODES * 16) x16[i] = __float2half(x[i]);
    if (i < NBUCK) bucket_cnt[i] = 0;
    if (i == 0) *spill_cnt = 0;
}

// counting-sort edges into 782 dst-buckets; entry = { (dstl<<17)|src , w_bits }
__global__ __launch_bounds__(256) void k_bin(const int* __restrict__ src,
                                             const int* __restrict__ dst,
                                             const float* __restrict__ w,
                                             int* __restrict__ bucket_cnt,
                                             uint2* __restrict__ ebuf,
                                             int4* __restrict__ sp,
                                             int* __restrict__ spill_cnt) {
    __shared__ int hist[NBUCK];
    __shared__ int base[NBUCK];
    __shared__ int rank[NBUCK];
    int tid = threadIdx.x;
    for (int b = tid; b < NBUCK; b += 256) { hist[b] = 0; rank[b] = 0; }
    __syncthreads();
    int e0 = blockIdx.x * EPB_BIN;
#pragma unroll 4
    for (int k = 0; k < 32; k++) {
        int e = e0 + tid + k * 256;
        if (e < N_EDGES) atomicAdd(&hist[__builtin_nontemporal_load(dst + e) >> 7], 1);
    }
    __syncthreads();
    for (int b = tid; b < NBUCK; b += 256) {
        int c = hist[b];
        base[b] = c ? atomicAdd(&bucket_cnt[b], c) : 0;
    }
    __syncthreads();
#pragma unroll 4
    for (int k = 0; k < 32; k++) {
        int e = e0 + tid + k * 256;
        if (e < N_EDGES) {
            int s = __builtin_nontemporal_load(src + e);
            int d = __builtin_nontemporal_load(dst + e);
            float wv = __builtin_nontemporal_load(w + e);
            int b = d >> 7;
            int r = atomicAdd(&rank[b], 1);
            int pos = base[b] + r;
            if (pos < BCAP) {
                ebuf[(size_t)b * BCAP + pos] =
                    make_uint2(((uint)(d & 127) << 17) | (uint)s, __float_as_uint(wv));
            } else {
                int oi = atomicAdd(spill_cnt, 1);
                if (oi < SPILL_MAX) sp[oi] = make_int4(s, d, __float_as_int(wv), 0);
            }
        }
    }
}

// per-bucket: stage in LDS, node-histogram + weighted degree, scatter to FIXED
// 64-slot node-major 4B entries (in place over the bucket's own region), zero-fill
// padding slots, write dinv. No prefix scan, no meta. Degree>64 -> global spill.
__global__ __launch_bounds__(256) void k_sort(uint2* __restrict__ ebuf,
                                              const int* __restrict__ bucket_cnt,
                                              int4* __restrict__ sp,
                                              int* __restrict__ spill_cnt,
                                              float* __restrict__ dinv) {
    __shared__ uint2 ent[BCAP];          // 38.4 KB
    __shared__ float wacc[BNODES];
    __shared__ int   hist[BNODES];
    __shared__ int   curs[BNODES];
    int b = blockIdx.x, tid = threadIdx.x;
    int lo = b * BNODES;
    int n = N_NODES - lo; if (n > BNODES) n = BNODES;
    if (tid < BNODES) { wacc[tid] = 0.0f; hist[tid] = 0; curs[tid] = tid * 64; }
    __syncthreads();
    int cnt = bucket_cnt[b]; if (cnt > BCAP) cnt = BCAP;
    const uint2* srcrow = ebuf + (size_t)b * BCAP;
    for (int j = tid; j < cnt; j += 256) {
        uint2 e = srcrow[j];
        ent[j] = e;
        int nl = e.x >> 17;
        atomicAdd(&hist[nl], 1);
        atomicAdd(&wacc[nl], __uint_as_float(e.y));
    }
    int ns0 = *spill_cnt; if (ns0 > SPILL_MAX) ns0 = SPILL_MAX;
    for (int i = tid; i < ns0; i += 256) {
        int4 q = sp[i];
        if ((q.y >> 7) == b) atomicAdd(&wacc[q.y & 127], __int_as_float(q.z));
    }
    __syncthreads();
    if (tid < n) dinv[lo + tid] = rsqrtf(1.0f + wacc[tid]);
    // scatter node-major fixed slots over the bucket's own region (source is in LDS)
    uint* outb = (uint*)ebuf + (size_t)b * (BCAP * 2);
    for (int j = tid; j < cnt; j += 256) {
        uint2 e = ent[j];
        int nl = e.x >> 17;
        int pos = atomicAdd(&curs[nl], 1);
        if (pos < nl * 64 + 64) {
            uint wq = __float2uint_rn(__uint_as_float(e.y) * WQSCALE);
            outb[pos] = (wq << 17) | (e.x & 0x1FFFF);
        } else {
            // rare overflow (degree > 64): push to global spill, handled by gathers
            int oi = atomicAdd(spill_cnt, 1);
            if (oi < SPILL_MAX)
                sp[oi] = make_int4((int)(e.x & 0x1FFFF), lo + nl, (int)e.y, 0);
        }
    }
    __syncthreads();
    // zero-fill padding slots (entry 0 == src 0 with weight exactly 0)
    for (int j = tid; j < BNODES * 64; j += 256) {
        int nl = j >> 6, sl = j & 63;
        if (sl >= hist[nl]) outb[j] = 0;
    }
}

// fold dinv[src] into each fixed-slot entry: q15(w) -> fp16-bits(dinv[s]*w)
// (positive fp16 < 1 has sign=0 -> the 16-bit pattern fits in 15 bits)
__global__ __launch_bounds__(256) void k_nrm(uint* __restrict__ sbuf,
                                             const float* __restrict__ dinv) {
    int b = blockIdx.x, tid = threadIdx.x;
    uint* outb = sbuf + (size_t)b * (BCAP * 2);
    for (int j = tid; j < BNODES * 64; j += 256) {
        uint e = outb[j];
        int s = e & 0x1FFFF;
        float wv = (float)(e >> 17) * (1.0f / WQSCALE);
        __half h = __float2half(dinv[s] * wv);
        uint q = (uint)__half_as_ushort(h);           // <= 0x3C00, fits 15 bits
        uint ne = (q << 17) | (uint)s;
        if (ne != e) outb[j] = ne;                    // pads stay 0, no store
    }
}

// fused: layer-1 gather (fixed-stride rows, 2 nodes/wave, packed fp16) + self + MLP.
__global__ __launch_bounds__(256) void k_gather_mlp(const uint* __restrict__ sbuf,
                                                    const int4* __restrict__ sp,
                                                    const int* __restrict__ spill_cnt,
                                                    const float* __restrict__ dinv,
                                                    const __half* __restrict__ x16,
                                                    const float* __restrict__ W1,
                                                    const float* __restrict__ b1,
                                                    const float* __restrict__ W2,
                                                    const float* __restrict__ b2,
                                                    __half* __restrict__ h2,
                                                    float* __restrict__ out) {
    __shared__ float fvs[8][16];
    __shared__ float o1s[4][128];
    int wave = threadIdx.x >> 6, lane = threadIdx.x & 63;
    int nsel = lane >> 5;            // which node of the wave's pair
    int c2   = lane & 1;             // feature half (8 halfs each)
    int eo   = (lane >> 1) & 15;     // slot group (4 slots each)
    int bid  = blockIdx.x;
    int local = ((bid >> 3) * 4 + wave) * 2 + nsel;  // node index within XCD slab
    int node  = (bid & 7) * NPX + local;
    bool alive = (local < NPX);
    float di = dinv[node];
    const uint* row = sbuf + srow(node);
    uint4 ev = *(const uint4*)(row + 4 * eo);        // 4 edge slots, one dwordx4
    int s0 = ev.x & 0x1FFFF, s1 = ev.y & 0x1FFFF;
    int s2 = ev.z & 0x1FFFF, s3 = ev.w & 0x1FFFF;
    uint4 hv0 = *(const uint4*)(x16 + (size_t)s0 * 16 + c2 * 8);
    uint4 hv1 = *(const uint4*)(x16 + (size_t)s1 * 16 + c2 * 8);
    uint4 hv2 = *(const uint4*)(x16 + (size_t)s2 * 16 + c2 * 8);
    uint4 hv3 = *(const uint4*)(x16 + (size_t)s3 * 16 + c2 * 8);
    __half2 q0 = __half2half2(__ushort_as_half((ushort)(ev.x >> 17)));
    __half2 q1 = __half2half2(__ushort_as_half((ushort)(ev.y >> 17)));
    __half2 q2 = __half2half2(__ushort_as_half((ushort)(ev.z >> 17)));
    __half2 q3 = __half2half2(__ushort_as_half((ushort)(ev.w >> 17)));
    __half2 acc[4];
    acc[0] = __hmul2(q0, as_h2(hv0.x));
    acc[1] = __hmul2(q0, as_h2(hv0.y));
    acc[2] = __hmul2(q0, as_h2(hv0.z));
    acc[3] = __hmul2(q0, as_h2(hv0.w));
    acc[0] = __hfma2(q1, as_h2(hv1.x), acc[0]);
    acc[1] = __hfma2(q1, as_h2(hv1.y), acc[1]);
    acc[2] = __hfma2(q1, as_h2(hv1.z), acc[2]);
    acc[3] = __hfma2(q1, as_h2(hv1.w), acc[3]);
    acc[0] = __hfma2(q2, as_h2(hv2.x), acc[0]);
    acc[1] = __hfma2(q2, as_h2(hv2.y), acc[1]);
    acc[2] = __hfma2(q2, as_h2(hv2.z), acc[2]);
    acc[3] = __hfma2(q2, as_h2(hv2.w), acc[3]);
    acc[0] = __hfma2(q3, as_h2(hv3.x), acc[0]);
    acc[1] = __hfma2(q3, as_h2(hv3.y), acc[1]);
    acc[2] = __hfma2(q3, as_h2(hv3.z), acc[2]);
    acc[3] = __hfma2(q3, as_h2(hv3.w), acc[3]);
    // reduce across 16 slot-groups (lane bits 1..4); stays within 32-lane node half
#pragma unroll
    for (int m = 2; m < 32; m <<= 1) {
#pragma unroll
        for (int k = 0; k < 4; k++)
            acc[k] = __hadd2(acc[k], as_h2(__shfl_xor(as_u32(acc[k]), m, 64)));
    }
    if (((lane & 31) < 2) && alive) {
        float accf[8];
#pragma unroll
        for (int k = 0; k < 4; k++) {
            float2 f = __half22float2(acc[k]);
            accf[2 * k + 0] = f.x;
            accf[2 * k + 1] = f.y;
        }
        uint4 hv = *(const uint4*)(x16 + (size_t)node * 16 + c2 * 8);
        float2 t0 = __half22float2(as_h2(hv.x));
        float2 t1 = __half22float2(as_h2(hv.y));
        float2 t2 = __half22float2(as_h2(hv.z));
        float2 t3 = __half22float2(as_h2(hv.w));
        float slf[8] = {t0.x, t0.y, t1.x, t1.y, t2.x, t2.y, t3.x, t3.y};
        float r[8];
#pragma unroll
        for (int k = 0; k < 8; k++) r[k] = accf[k] + di * slf[k];
        int ns = *spill_cnt;                       // 0 in practice
        if (ns > 0) {
            if (ns > SPILL_MAX) ns = SPILL_MAX;
            for (int i = 0; i < ns; i++) {
                int4 q = sp[i];
                if (q.y == node) {
                    float f = dinv[q.x] * __int_as_float(q.z);
                    uint4 qv = *(const uint4*)(x16 + (size_t)q.x * 16 + c2 * 8);
                    float2 u0 = __half22float2(as_h2(qv.x));
                    float2 u1 = __half22float2(as_h2(qv.y));
                    float2 u2 = __half22float2(as_h2(qv.z));
                    float2 u3 = __half22float2(as_h2(qv.w));
                    float uv[8] = {u0.x, u0.y, u1.x, u1.y, u2.x, u2.y, u3.x, u3.y};
                    for (int k = 0; k < 8; k++) r[k] += f * uv[k];
                }
            }
        }
#pragma unroll
        for (int k = 0; k < 8; k++) fvs[wave * 2 + nsel][c2 * 8 + k] = r[k] * di;
    }
    __syncthreads();
    // MLP for the wave's 2 nodes, sequentially (same total FLOPs)
    for (int t = 0; t < 2; t++) {
        int lnode = ((bid >> 3) * 4 + wave) * 2 + t;
        int mnode = (bid & 7) * NPX + lnode;
        bool alv = (lnode < NPX);
        float fv[16];
#pragma unroll
        for (int k = 0; k < 16; k++) fv[k] = fvs[wave * 2 + t][k];
        float a = b1[2 * lane], bb = b1[2 * lane + 1];
#pragma unroll
        for (int k = 0; k < 16; k++) {
            float2 wv = *(const float2*)(W1 + k * 128 + 2 * lane);
            a = fmaf(fv[k], wv.x, a);
            bb = fmaf(fv[k], wv.y, bb);
        }
        __syncthreads();                 // protect o1s reuse across t
        o1s[wave][2 * lane + 0] = fmaxf(a, 0.0f);
        o1s[wave][2 * lane + 1] = fmaxf(bb, 0.0f);
        __syncthreads();
        int c = lane & 15, g = lane >> 4;
        float p = 0.0f;
#pragma unroll
        for (int k = 0; k < 32; k++) {
            int kk = g * 32 + k;
            p = fmaf(o1s[wave][kk], W2[kk * 16 + c], p);
        }
        p += __shfl_down(p, 16, 64);
        p += __shfl_down(p, 32, 64);
        if (lane < 16 && alv) {
            float dt = dinv[mnode];
            h2[(size_t)mnode * 16 + c] = __float2half(p);
            out[(size_t)mnode * 16 + c] = dt * dt * p + b2[c];
        }
    }
}

// layer-2 gather: out[node] += di * (sum q*h2[s] + spill); fixed rows, 2 nodes/wave.
__global__ __launch_bounds__(256) void k_gather2(const uint* __restrict__ sbuf,
                                                 const int4* __restrict__ sp,
                                                 const int* __restrict__ spill_cnt,
                                                 const float* __restrict__ dinv,
                                                 const __half* __restrict__ h2,
                                                 float* __restrict__ out) {
    int wave = threadIdx.x >> 6, lane = threadIdx.x & 63;
    int nsel = lane >> 5;
    int c2   = lane & 1;
    int eo   = (lane >> 1) & 15;
    int bid  = blockIdx.x;
    int local = ((bid >> 3) * 4 + wave) * 2 + nsel;
    int node  = (bid & 7) * NPX + local;
    bool alive = (local < NPX);
    float di = dinv[node];
    const uint* row = sbuf + srow(node);
    uint4 ev = *(const uint4*)(row + 4 * eo);
    int s0 = ev.x & 0x1FFFF, s1 = ev.y & 0x1FFFF;
    int s2 = ev.z & 0x1FFFF, s3 = ev.w & 0x1FFFF;
    uint4 hv0 = *(const uint4*)(h2 + (size_t)s0 * 16 + c2 * 8);
    uint4 hv1 = *(const uint4*)(h2 + (size_t)s1 * 16 + c2 * 8);
    uint4 hv2 = *(const uint4*)(h2 + (size_t)s2 * 16 + c2 * 8);
    uint4 hv3 = *(const uint4*)(h2 + (size_t)s3 * 16 + c2 * 8);
    __half2 q0 = __half2half2(__ushort_as_half((ushort)(ev.x >> 17)));
    __half2 q1 = __half2half2(__ushort_as_half((ushort)(ev.y >> 17)));
    __half2 q2 = __half2half2(__ushort_as_half((ushort)(ev.z >> 17)));
    __half2 q3 = __half2half2(__ushort_as_half((ushort)(ev.w >> 17)));
    __half2 acc[4];
    acc[0] = __hmul2(q0, as_h2(hv0.x));
    acc[1] = __hmul2(q0, as_h2(hv0.y));
    acc[2] = __hmul2(q0, as_h2(hv0.z));
    acc[3] = __hmul2(q0, as_h2(hv0.w));
    acc[0] = __hfma2(q1, as_h2(hv1.x), acc[0]);
    acc[1] = __hfma2(q1, as_h2(hv1.y), acc[1]);
    acc[2] = __hfma2(q1, as_h2(hv1.z), acc[2]);
    acc[3] = __hfma2(q1, as_h2(hv1.w), acc[3]);
    acc[0] = __hfma2(q2, as_h2(hv2.x), acc[0]);
    acc[1] = __hfma2(q2, as_h2(hv2.y), acc[1]);
    acc[2] = __hfma2(q2, as_h2(hv2.z), acc[2]);
    acc[3] = __hfma2(q2, as_h2(hv2.w), acc[3]);
    acc[0] = __hfma2(q3, as_h2(hv3.x), acc[0]);
    acc[1] = __hfma2(q3, as_h2(hv3.y), acc[1]);
    acc[2] = __hfma2(q3, as_h2(hv3.z), acc[2]);
    acc[3] = __hfma2(q3, as_h2(hv3.w), acc[3]);
#pragma unroll
    for (int m = 2; m < 32; m <<= 1) {
#pragma unroll
        for (int k = 0; k < 4; k++)
            acc[k] = __hadd2(acc[k], as_h2(__shfl_xor(as_u32(acc[k]), m, 64)));
    }
    if (((lane & 31) < 2) && alive) {
        float accf[8];
#pragma unroll
        for (int k = 0; k < 4; k++) {
            float2 f = __half22float2(acc[k]);
            accf[2 * k + 0] = f.x;
            accf[2 * k + 1] = f.y;
        }
        int ns = *spill_cnt;
        if (ns > 0) {
            if (ns > SPILL_MAX) ns = SPILL_MAX;
            for (int i = 0; i < ns; i++) {
                int4 q = sp[i];
                if (q.y == node) {
                    float f = dinv[q.x] * __int_as_float(q.z);
                    uint4 qv = *(const uint4*)(h2 + (size_t)q.x * 16 + c2 * 8);
                    float2 u0 = __half22float2(as_h2(qv.x));
                    float2 u1 = __half22float2(as_h2(qv.y));
                    float2 u2 = __half22float2(as_h2(qv.z));
                    float2 u3 = __half22float2(as_h2(qv.w));
                    float uv[8] = {u0.x, u0.y, u1.x, u1.y, u2.x, u2.y, u3.x, u3.y};
                    for (int k = 0; k < 8; k++) accf[k] += f * uv[k];
                }
            }
        }
        float4* op = (float4*)(out + (size_t)node * 16 + c2 * 8);
        float4 o0 = op[0], o1 = op[1];
        o0.x += di * accf[0]; o0.y += di * accf[1];
        o0.z += di * accf[2]; o0.w += di * accf[3];
        o1.x += di * accf[4]; o1.y += di * accf[5];
        o1.z += di * accf[6]; o1.w += di * accf[7];
        op[0] = o0; op[1] = o1;
    }
}

// ===================== CSR fallback (round-2) =====================

__global__ void k_init(float* __restrict__ deg, int* __restrict__ cnt) {
    int i = blockIdx.x * blockDim.x + threadIdx.x;
    if (i < N_NODES) { deg[i] = 1.0f; if (cnt) cnt[i] = 0; }
}

__global__ void k_degcnt(const int* __restrict__ dst, const float* __restrict__ w,
                         float* __restrict__ deg, int* __restrict__ cnt) {
    int e = blockIdx.x * blockDim.x + threadIdx.x;
    if (e < N_EDGES) {
        int d = dst[e];
        atomicAdd(&deg[d], w[e]);
        if (cnt) atomicAdd(&cnt[d], 1);
    }
}

__global__ void k_dinv_agg(const float* __restrict__ x, float* __restrict__ deg_dinv,
                           float* __restrict__ agg) {
    int i = blockIdx.x * blockDim.x + threadIdx.x;
    if (i >= N_NODES) return;
    float di = rsqrtf(deg_dinv[i]);
    deg_dinv[i] = di;
    float s = di * di;
    const float4* xr = (const float4*)(x + (size_t)i * 16);
    float4* ar = (float4*)(agg + (size_t)i * 16);
#pragma unroll
    for (int k = 0; k < 4; k++) {
        float4 v = xr[k];
        v.x *= s; v.y *= s; v.z *= s; v.w *= s;
        ar[k] = v;
    }
}

__global__ __launch_bounds__(256) void k_scan1(const int* __restrict__ cnt,
                                               int* __restrict__ rowptr,
                                               int* __restrict__ bsum) {
    __shared__ int ts[256];
    int tid = threadIdx.x;
    int base = blockIdx.x * SCAN_CHUNK + tid * 8;
    int v[8]; int s = 0;
#pragma unroll
    for (int k = 0; k < 8; k++) {
        int idx = base + k;
        v[k] = (idx < N_NODES) ? cnt[idx] : 0;
        s += v[k];
    }
    ts[tid] = s;
    __syncthreads();
    for (int off = 1; off < 256; off <<= 1) {
        int t = (tid >= off) ? ts[tid - off] : 0;
        __syncthreads();
        ts[tid] += t;
        __syncthreads();
    }
    int run = ts[tid] - s;
#pragma unroll
    for (int k = 0; k < 8; k++) {
        int idx = base + k;
        if (idx < N_NODES) rowptr[idx] = run;
        run += v[k];
    }
    if (tid == 255) bsum[blockIdx.x] = ts[255];
}

__global__ void k_scan2(int* __restrict__ bsum) {
    if (threadIdx.x == 0 && blockIdx.x == 0) {
        int run = 0;
        for (int g = 0; g < SCAN_BLOCKS; g++) { int t = bsum[g]; bsum[g] = run; run += t; }
    }
}

__global__ __launch_bounds__(256) void k_scan3(int* __restrict__ rowptr,
                                               const int* __restrict__ bsum) {
    int tid = threadIdx.x;
    int base = blockIdx.x * SCAN_CHUNK + tid * 8;
    int off = bsum[blockIdx.x];
#pragma unroll
    for (int k = 0; k < 8; k++) {
        int idx = base + k;
        if (idx < N_NODES) rowptr[idx] += off;
    }
    if (blockIdx.x == 0 && tid == 0) rowptr[N_NODES] = N_EDGES;
}

__global__ void k_fill(const int* __restrict__ src, const int* __restrict__ dst,
                       const float* __restrict__ w, const float* __restrict__ dinv,
                       const int* __restrict__ rowptr, int* __restrict__ cnt,
                       int2* __restrict__ perm) {
    int e = blockIdx.x * blockDim.x + threadIdx.x;
    if (e >= N_EDGES) return;
    int s = src[e], d = dst[e];
    float nrm = dinv[s] * w[e] * dinv[d];
    int r = atomicSub(&cnt[d], 1) - 1;
    int pos = rowptr[d] + r;
    perm[pos] = make_int2(s, __float_as_int(nrm));
}

__global__ __launch_bounds__(256) void k_gather(const int2* __restrict__ perm,
                                                const int* __restrict__ rowptr,
                                                const float* __restrict__ feat,
                                                float* __restrict__ out) {
    int wave = threadIdx.x >> 6, lane = threadIdx.x & 63;
    int node = blockIdx.x * 4 + wave;
    int c = lane & 15, eo = lane >> 4;
    int beg = rowptr[node], end = rowptr[node + 1];
    float acc = 0.0f;
    for (int j = beg + eo; j < end; j += 4) {
        int2 ed = perm[j];
        acc = fmaf(__int_as_float(ed.y), feat[(size_t)ed.x * 16 + c], acc);
    }
    acc += __shfl_xor(acc, 16, 64);
    acc += __shfl_xor(acc, 32, 64);
    if (lane < 16) out[(size_t)node * 16 + c] += acc;
}

__global__ __launch_bounds__(256) void k_mlp(float* __restrict__ agg,
                                             const float* __restrict__ W1,
                                             const float* __restrict__ b1,
                                             const float* __restrict__ W2,
                                             const float* __restrict__ b2,
                                             const float* __restrict__ dinv,
                                             float* __restrict__ out) {
    __shared__ float o1s[4][128];
    int wave = threadIdx.x >> 6;
    int lane = threadIdx.x & 63;
    int node = blockIdx.x * 4 + wave;
    const float* f = agg + (size_t)node * 16;
    float fv[16];
#pragma unroll
    for (int k = 0; k < 4; k++) {
        float4 v = ((const float4*)f)[k];
        fv[4 * k + 0] = v.x; fv[4 * k + 1] = v.y; fv[4 * k + 2] = v.z; fv[4 * k + 3] = v.w;
    }
    float a = b1[2 * lane], b = b1[2 * lane + 1];
#pragma unroll
    for (int k = 0; k < 16; k++) {
        float2 wv = *(const float2*)(W1 + k * 128 + 2 * lane);
        a = fmaf(fv[k], wv.x, a);
        b = fmaf(fv[k], wv.y, b);
    }
    o1s[wave][2 * lane + 0] = fmaxf(a, 0.0f);
    o1s[wave][2 * lane + 1] = fmaxf(b, 0.0f);
    __syncthreads();
    int c = lane & 15, g = lane >> 4;
    float p = 0.0f;
#pragma unroll
    for (int k = 0; k < 32; k++) {
        int kk = g * 32 + k;
        p = fmaf(o1s[wave][kk], W2[kk * 16 + c], p);
    }
    p += __shfl_down(p, 16, 64);
    p += __shfl_down(p, 32, 64);
    __syncthreads();
    if (lane < 16) {
        float h2v = p;
        agg[(size_t)node * 16 + c] = h2v;
        float di = dinv[node];
        out[(size_t)node * 16 + c] = di * di * h2v + b2[c];
    }
}

__global__ void k_scatter(const int* __restrict__ src, const int* __restrict__ dst,
                          const float* __restrict__ w, const float* __restrict__ dinv,
                          const float* __restrict__ feat, float* __restrict__ out) {
    int t = blockIdx.x * blockDim.x + threadIdx.x;
    int e = t >> 2;
    int c4 = (t & 3) * 4;
    if (e >= N_EDGES) return;
    int s = src[e], d = dst[e];
    float nrm = dinv[s] * w[e] * dinv[d];
    float4 v = *(const float4*)(feat + (size_t)s * 16 + c4);
    float* o = out + (size_t)d * 16 + c4;
    atomicAdd(o + 0, nrm * v.x);
    atomicAdd(o + 1, nrm * v.y);
    atomicAdd(o + 2, nrm * v.z);
    atomicAdd(o + 3, nrm * v.w);
}

// ===================== launch =====================

extern "C" void kernel_launch(void* const* d_in, const int* in_sizes, int n_in,
                              void* d_out, int out_size, void* d_ws, size_t ws_size,
                              hipStream_t stream) {
    const float* x  = (const float*)d_in[0];
    const int*   ei = (const int*)d_in[1];
    const float* w  = (const float*)d_in[2];
    const float* W1 = (const float*)d_in[3];
    const float* b1 = (const float*)d_in[4];
    const float* W2 = (const float*)d_in[5];
    const float* b2 = (const float*)d_in[6];
    float* out = (float*)d_out;

    const int* src = ei;
    const int* dst = ei + N_EDGES;
    const int B = 256;

    // ---- fast-path workspace layout (16B-aligned blocks) ----
    char* p = (char*)d_ws;
    int*    bucket_cnt = (int*)p;        p += (size_t)((NBUCK + 3) & ~3) * 4;
    int*    spill_cnt  = (int*)p;        p += 16;
    float*  dinv       = (float*)p;      p += (size_t)N_PAD * 4;
    __half* x16        = (__half*)p;     p += (size_t)N_NODES * 16 * 2;
    __half* h2         = (__half*)p;     p += (size_t)N_NODES * 16 * 2;
    int4*   sp         = (int4*)p;       p += (size_t)SPILL_MAX * 16;
    uint2*  ebuf       = (uint2*)p;      p += (size_t)NBUCK * BCAP * 8;
    const size_t WS_FAST = (size_t)(p - (char*)d_ws);

    if (ws_size >= WS_FAST) {
        k_pre<<<(N_NODES * 16 + B - 1) / B, B, 0, stream>>>(x, x16, bucket_cnt, spill_cnt);
        k_bin<<<BIN_BLOCKS, B, 0, stream>>>(src, dst, w, bucket_cnt, ebuf, sp, spill_cnt);
        k_sort<<<NBUCK, B, 0, stream>>>(ebuf, bucket_cnt, sp, spill_cnt, dinv);
        k_nrm<<<NBUCK, B, 0, stream>>>((uint*)ebuf, dinv);
        k_gather_mlp<<<GBLK, B, 0, stream>>>((const uint*)ebuf,
                                             sp, spill_cnt, dinv, x16,
                                             W1, b1, W2, b2, h2, out);
        k_gather2<<<GBLK, B, 0, stream>>>((const uint*)ebuf,
                                          sp, spill_cnt, dinv, h2, out);
        return;
    }

    // ---- CSR fallback (round-2 path) ----
    float* deg_dinv = (float*)d_ws;
    int*   cntb     = (int*)(deg_dinv + N_PAD);
    int*   rowptr   = cntb + N_PAD;
    int*   bsum     = rowptr + N_PAD;
    float* agg      = (float*)(bsum + 64);
    int2*  perm     = (int2*)(agg + (size_t)N_NODES * 16);
    const size_t WS_CSR = ((size_t)N_PAD * 3 + 64 + (size_t)N_NODES * 16) * 4
                          + (size_t)N_EDGES * 8;

    if (ws_size >= WS_CSR) {
        k_init<<<(N_NODES + B - 1) / B, B, 0, stream>>>(deg_dinv, cntb);
        k_degcnt<<<(N_EDGES + B - 1) / B, B, 0, stream>>>(dst, w, deg_dinv, cntb);
        k_dinv_agg<<<(N_NODES + B - 1) / B, B, 0, stream>>>(x, deg_dinv, agg);
        k_scan1<<<SCAN_BLOCKS, 256, 0, stream>>>(cntb, rowptr, bsum);
        k_scan2<<<1, 64, 0, stream>>>(bsum);
        k_scan3<<<SCAN_BLOCKS, 256, 0, stream>>>(rowptr, bsum);
        k_fill<<<(N_EDGES + B - 1) / B, B, 0, stream>>>(src, dst, w, deg_dinv,
                                                        rowptr, cntb, perm);
        k_gather<<<N_NODES / 4, B, 0, stream>>>(perm, rowptr, x, agg);
        k_mlp<<<N_NODES / 4, B, 0, stream>>>(agg, W1, b1, W2, b2, deg_dinv, out);
        k_gather<<<N_NODES / 4, B, 0, stream>>>(perm, rowptr, agg, out);
    } else {
        float* deg = (float*)d_ws;
        float* ag  = (float*)d_ws + N_NODES;
        k_init<<<(N_NODES + B - 1) / B, B, 0, stream>>>(deg, (int*)nullptr);
        k_degcnt<<<(N_EDGES + B - 1) / B, B, 0, stream>>>(dst, w, deg, (int*)nullptr);
        k_dinv_agg<<<(N_NODES + B - 1) / B, B, 0, stream>>>(x, deg, ag);
        k_scatter<<<((size_t)N_EDGES * 4 + B - 1) / B, B, 0, stream>>>(src, dst, w, deg, x, ag);
        k_mlp<<<N_NODES / 4, B, 0, stream>>>(ag, W1, b1, W2, b2, deg, out);
        k_scatter<<<((size_t)N_EDGES * 4 + B - 1) / B, B, 0, stream>>>(src, dst, w, deg, ag, out);
    }
}